// Round 13
// baseline (245.721 us; speedup 1.0000x reference)
//
#include <hip/hip_runtime.h>

typedef __bf16 bf16_t;
typedef __bf16 bf16x8 __attribute__((ext_vector_type(8)));
typedef __bf16 bf16x4 __attribute__((ext_vector_type(4)));
typedef float  f32x4  __attribute__((ext_vector_type(4)));

// ---------------------------------------------------------------------------
// Workspace layout (floats unless noted):
//   Ap : [64][16384] f32  xf@W1[0:26] in h-FRAGMENT-LINEAR order:
//        slot ((jt*8+it)*64 + q*16 + r)*8 + e = A[b][jt*16+r][it*32+q*8+e]
//        -> build reads are lane-contiguous (r10: worth ~2us).        4 MB
//   C  : [4096][256] f32  (xf @ W1[26:52] + qst @ W1[52:180] + b1)    4 MB
//   Wt : 3 x [256][256] bf16 in MFMA A-fragment layout:
//        [mat][tile16(no>>4)][ks(k>>5)][lane(q*16+r)][e]; per-(tile,ks)
//        wave load is one coalesced 1 KB transaction.                 384 KB
//   part : [4096][256] f32  per-block partial pair-sums               4 MB
//
// h in LDS: B-fragment-linear  h[chunk = mt*8+ks][lane = q*16+r][e]
//   <-> h[m = mt*16+r][k = ks*32+q*8+e]  -> all LDS ops lane-contiguous,
//   zero bank conflicts by construction.
//
// Round 13 = r12's 3-barrier ping-pong skeleton (137->123.5us, MfmaUtil
// 32->36.4 -- confirmed: duty scales with barrier density) + r8's
// register-stationary W, now affordable at 2 waves/SIMD because M=64
// shrinks acc to 64 AGPR: wreg 128 + acc 64 + hf 16 + misc ~30 = ~238
// of the 256-reg budget.  Per-CU W streaming (256 KB/layer from L1 ~4096
// cyc, at parity with the 4966-cyc MFMA pipe) leaves the inner loop:
// wreg-L0 loads issue BEFORE build (hidden under build+barrier); wreg-L+1
// loads issue after L's epilogue (hidden under epilogue+barrier+skew).
// Inner loop = 4 LDS reads + 16 MFMA, zero global.
// Race audit (same as r12): build->hA |bar| L0 rd hA wr hB |bar| L1 rd hB
// wr hA |bar| L2 rd hA -> disjoint read/write sets between barriers;
// all barriers block-uniform.  Spill check: WRITE_SIZE must stay ~4 MB.
// ---------------------------------------------------------------------------

// ---------------- prep: Ap, C, weight fragment-relayout ---------------------
__global__ __launch_bounds__(256) void rn_prep_kernel(
    const float* __restrict__ x, const float* __restrict__ qst,
    const float* __restrict__ g1w, const float* __restrict__ g1b,
    const float* __restrict__ g2w, const float* __restrict__ g3w,
    const float* __restrict__ g4w,
    float* __restrict__ Ap, float* __restrict__ C,
    bf16_t* __restrict__ Wt)
{
  __shared__ float T[64][65];   // transpose tile (only used by that branch)
  int blk = blockIdx.x;
  int n   = threadIdx.x;  // 0..255
  if (blk < 256) {
    // block = (b, jg): rows jg*16 .. jg*16+15 of batch b; thread = output col n
    int b  = blk >> 2;
    int jg = (blk & 3) * 16;
    float accQ = g1b[n];
    const float* qb = qst + b * 128;
    #pragma unroll 8
    for (int qi = 0; qi < 128; ++qi)
      accQ += qb[qi] * g1w[(52 + qi) * 256 + n];

    float w24 = g1w[24 * 256 + n], w25 = g1w[25 * 256 + n];
    float w50 = g1w[50 * 256 + n], w51 = g1w[51 * 256 + n];
    float accA[16], accC[16];
    #pragma unroll
    for (int t = 0; t < 16; ++t) {
      int j = jg + t;
      // faithful to (a/d - d/2)/(d/2.0) float arithmetic, d=8 (exact pow2 ops)
      float cx = ((float)j * 0.125f - 4.0f) * 0.25f;
      float cy = ((float)(j & 7) - 4.0f) * 0.25f;
      accA[t] = cx * w24 + cy * w25;
      accC[t] = accQ + cx * w50 + cy * w51;
    }
    for (int c = 0; c < 24; ++c) {
      float wa = g1w[c * 256 + n];
      float wc = g1w[(26 + c) * 256 + n];
      const float* xc = x + (b * 24 + c) * 64 + jg;
      #pragma unroll
      for (int t = 0; t < 16; ++t) {
        float xv = xc[t];   // uniform per thread -> scalar load
        accA[t] += xv * wa;
        accC[t] += xv * wc;
      }
    }
    // A in fragment-linear order: j = jt*16 + t (jt = blk&3, r = t), k = n.
    int jt = blk & 3;
    int itA = n >> 5, qA = (n >> 3) & 3, eA = n & 7;
    int baseA = b * 16384 + (jt * 8 + itA) * 512 + qA * 128 + eA;
    #pragma unroll
    for (int t = 0; t < 16; ++t) {
      Ap[baseA + t * 8] = accA[t];
      C[(b * 64 + jg + t) * 256 + n] = accC[t];
    }
  } else {
    // LDS-tiled transpose: g2/g3/g4 [in(k)][out(no)] f32 -> bf16 fragment
    // layout: element (no,k) -> [(no>>4)*8 + (k>>5)][((k>>3)&3)*16 + (no&15)][k&7]
    int t   = blk - 256;
    int mat = t >> 4;                 // 0..2
    int tl  = t & 15;                 // 4x4 tiles of 64x64
    int kt  = (tl & 3) * 64;
    int nt_ = (tl >> 2) * 64;
    const float* W = (mat == 0) ? g2w : (mat == 1 ? g3w : g4w);
    int lane = n & 63, w = n >> 6;
    #pragma unroll
    for (int it = 0; it < 16; ++it) {
      int kl = w * 16 + it;
      T[kl][lane] = W[(kt + kl) * 256 + nt_ + lane];   // coalesced 256B/wave
    }
    __syncthreads();
    #pragma unroll
    for (int it = 0; it < 16; ++it) {
      int nl  = w * 16 + it;
      int no  = nt_ + nl;     // output-neuron index
      int k   = kt + lane;    // input index
      int tile = no >> 4, rr = no & 15;
      int ksI  = k >> 5,  qI = (k >> 3) & 3, e = k & 7;
      int idx  = ((tile * 8 + ksI) * 64 + qI * 16 + rr) * 8 + e;
      Wt[mat * 65536 + idx] = (bf16_t)T[lane][nl];
    }
  }
}

// ---------------- main fused g-MLP (layers 2..4) + pair partial-sum --------
// one block per (b, i): M = 64 rows, N = K = 256, 4 waves.
// Wave w owns n-rows [w*64, w*64+64) (nt=0..3) and all 64 m-rows (mt=0..3).
// Register-stationary W: wave's 16 KB layer slice lives in wreg[4][8]
// (128 VGPR), reloaded once per layer OUTSIDE the inner loop.
// Per ks: 4 hf LDS reads (lane-contiguous) + 16 MFMA -- zero global.
// Ping-pong: build->hA; L0 rd hA wr hB; L1 rd hB wr hA; L2 rd hA -> store.
__global__ __launch_bounds__(256, 2) void rn_main_kernel(
    const float* __restrict__ Ap, const float* __restrict__ C,
    const bf16_t* __restrict__ Wt,
    const float* __restrict__ g2b, const float* __restrict__ g3b,
    const float* __restrict__ g4b,
    float* __restrict__ part)
{
  __shared__ bf16_t hA[16384];   // 32 KB: [chunk=mt*8+ks][lane][8]
  __shared__ bf16_t hB[16384];   // 32 KB

  int tid  = threadIdx.x;
  int bx0  = blockIdx.x;
  // bijective XCD swizzle (4096 % 8 == 0): 512 consecutive work-units per
  // XCD -> the 64 blocks sharing a batch b stay on one XCD's L2
  int bx   = (bx0 & 7) * 512 + (bx0 >> 3);
  int b    = bx >> 6;          // batch
  int i    = bx & 63;          // i-object
  int lane = tid & 63;
  int wave = tid >> 6;
  int r    = lane & 15;        // 16-dim index within MFMA tile
  int q    = lane >> 4;        // quad: k-run selector / D-row group

  bf16x8 wreg[4][8];           // this wave's 16 KB W slice (128 VGPR)

#define LOAD_WREG(LL)                                                       \
  {                                                                         \
    const bf16_t* Wl = Wt + (LL) * 65536 + wave * 16384;                    \
    _Pragma("unroll")                                                       \
    for (int nt = 0; nt < 4; ++nt)                                          \
      _Pragma("unroll")                                                     \
      for (int ks = 0; ks < 8; ++ks)                                        \
        wreg[nt][ks] = *(const bf16x8*)&Wl[((nt * 8 + ks) * 64 + lane) * 8];\
  }

  // issue L0's W loads FIRST: their latency hides under the whole build.
  LOAD_WREG(0)

  // ---- build h rows into hA (fragment-linear) ----
  // wave w builds chunks (mt=w, ks=it).  Ap is pre-arranged so the A read is
  // lane-contiguous; C row i is a cheap broadcast.
  {
    const float* Apb = Ap + (size_t)b * 16384 + wave * 4096;
    const float* Cr  = C + ((size_t)b * 64 + i) * 256;
    #pragma unroll
    for (int it = 0; it < 8; ++it) {
      int k0 = it * 32 + q * 8;
      const float4 a0 = *(const float4*)(Apb + it * 512 + lane * 8);
      const float4 a1 = *(const float4*)(Apb + it * 512 + lane * 8 + 4);
      const float4 c0 = *(const float4*)(Cr + k0);
      const float4 c1 = *(const float4*)(Cr + k0 + 4);
      bf16x8 v;
      v[0] = (bf16_t)fmaxf(a0.x + c0.x, 0.f);
      v[1] = (bf16_t)fmaxf(a0.y + c0.y, 0.f);
      v[2] = (bf16_t)fmaxf(a0.z + c0.z, 0.f);
      v[3] = (bf16_t)fmaxf(a0.w + c0.w, 0.f);
      v[4] = (bf16_t)fmaxf(a1.x + c1.x, 0.f);
      v[5] = (bf16_t)fmaxf(a1.y + c1.y, 0.f);
      v[6] = (bf16_t)fmaxf(a1.z + c1.z, 0.f);
      v[7] = (bf16_t)fmaxf(a1.w + c1.w, 0.f);
      *(bf16x8*)&hA[((wave * 8 + it) * 64 + lane) * 8] = v;
    }
  }
  __syncthreads();             // hA complete

  #pragma unroll
  for (int L = 0; L < 3; ++L) {
    const bf16_t* hs = (L == 1) ? hB : hA;   // compile-time under unroll
    bf16_t*       hd = (L == 0) ? hB : hA;
    const float*  bias = (L == 0) ? g2b : (L == 1) ? g3b : g4b;

    f32x4 acc[4][4];           // [nt][mt]
    #pragma unroll
    for (int nt = 0; nt < 4; ++nt)
      #pragma unroll
      for (int mt = 0; mt < 4; ++mt)
        #pragma unroll
        for (int e = 0; e < 4; ++e) acc[nt][mt][e] = 0.f;

    #pragma unroll
    for (int ks = 0; ks < 8; ++ks) {
      bf16x8 hf[4];
      #pragma unroll
      for (int mt = 0; mt < 4; ++mt)
        hf[mt] = *(const bf16x8*)&hs[((mt * 8 + ks) * 64 + lane) * 8];
      __builtin_amdgcn_s_setprio(1);
      #pragma unroll
      for (int nt = 0; nt < 4; ++nt)
        #pragma unroll
        for (int mt = 0; mt < 4; ++mt)
          acc[nt][mt] = __builtin_amdgcn_mfma_f32_16x16x32_bf16(
              wreg[nt][ks], hf[mt], acc[nt][mt], 0, 0, 0);
      __builtin_amdgcn_s_setprio(0);
    }
    // NO barrier here: reads were from hs, writes go to hd (disjoint).

    if (L < 2) {
      // D value (nt,mt,e): n = wave*64+nt*16+q*4+e (next layer's k),
      // m = mt*16+r.  Fragment-linear write into hd.
      #pragma unroll
      for (int nt = 0; nt < 4; ++nt) {
        int k0  = wave * 64 + nt * 16 + q * 4;
        float4 bv = *(const float4*)&bias[k0];
        int ks_ = k0 >> 5, rem = k0 & 31;
        int qp  = rem >> 3, e0 = rem & 7;     // e0 in {0,4}
        #pragma unroll
        for (int mt = 0; mt < 4; ++mt) {
          bf16x4 v;
          v[0] = (bf16_t)fmaxf(acc[nt][mt][0] + bv.x, 0.f);
          v[1] = (bf16_t)fmaxf(acc[nt][mt][1] + bv.y, 0.f);
          v[2] = (bf16_t)fmaxf(acc[nt][mt][2] + bv.z, 0.f);
          v[3] = (bf16_t)fmaxf(acc[nt][mt][3] + bv.w, 0.f);
          int off = ((mt * 8 + ks_) * 64 + qp * 16 + r) * 8 + e0;
          *(bf16x4*)&hd[off] = v;
        }
      }
      // refill wreg for the NEXT layer after its last use above; the load
      // latency hides under the barrier + the next layer's first LDS reads.
      if (L == 0) LOAD_WREG(1)
      else        LOAD_WREG(2)
      __syncthreads();         // hd complete before next layer reads it
    } else {
      // last layer: bias+relu fp32, sum over the 64 m-rows (mt in-register,
      // then the 16 r-lanes), plain float4 partial store (no atomics).
      #pragma unroll
      for (int nt = 0; nt < 4; ++nt) {
        int k0 = wave * 64 + nt * 16 + q * 4;
        float4 bv = *(const float4*)&bias[k0];
        float p0 = 0.f, p1 = 0.f, p2 = 0.f, p3 = 0.f;
        #pragma unroll
        for (int mt = 0; mt < 4; ++mt) {
          p0 += fmaxf(acc[nt][mt][0] + bv.x, 0.f);
          p1 += fmaxf(acc[nt][mt][1] + bv.y, 0.f);
          p2 += fmaxf(acc[nt][mt][2] + bv.z, 0.f);
          p3 += fmaxf(acc[nt][mt][3] + bv.w, 0.f);
        }
        #pragma unroll
        for (int d = 1; d < 16; d <<= 1) {
          p0 += __shfl_xor(p0, d, 64);
          p1 += __shfl_xor(p1, d, 64);
          p2 += __shfl_xor(p2, d, 64);
          p3 += __shfl_xor(p3, d, 64);
        }
        if (r == 0) {
          float4 pv = make_float4(p0, p1, p2, p3);
          *(float4*)&part[(size_t)bx * 256 + k0] = pv;
        }
      }
    }
  }
#undef LOAD_WREG
}

// ---------------- partial reduce + f-MLP + log_softmax (tiny, fp32) --------
__global__ __launch_bounds__(256) void rn_f_kernel(
    const float* __restrict__ part,
    const float* __restrict__ f1w, const float* __restrict__ f1b,
    const float* __restrict__ f2w, const float* __restrict__ f2b,
    const float* __restrict__ f3w, const float* __restrict__ f3b,
    float* __restrict__ out)
{
  __shared__ float xs[256], t1[256], t2[256], lg[28], lse[1];
  int b = blockIdx.x, tid = threadIdx.x;
  // reduce the 64 per-i partials of batch b (coalesced 1 KB/wave per iter)
  float s = 0.f;
  const float* pb = part + (size_t)b * 64 * 256;
  #pragma unroll 8
  for (int i = 0; i < 64; ++i) s += pb[i * 256 + tid];
  xs[tid] = s;
  __syncthreads();
  float acc = f1b[tid];
  for (int k = 0; k < 256; ++k) acc += xs[k] * f1w[k * 256 + tid];
  t1[tid] = fmaxf(acc, 0.f);
  __syncthreads();
  acc = f2b[tid];
  for (int k = 0; k < 256; ++k) acc += t1[k] * f2w[k * 256 + tid];
  t2[tid] = fmaxf(acc, 0.f);
  __syncthreads();
  if (tid < 28) {
    float a2 = f3b[tid];
    for (int k = 0; k < 256; ++k) a2 += t2[k] * f3w[k * 28 + tid];
    lg[tid] = a2;
  }
  __syncthreads();
  if (tid == 0) {
    float m = lg[0];
    for (int j = 1; j < 28; ++j) m = fmaxf(m, lg[j]);
    float se = 0.f;
    for (int j = 0; j < 28; ++j) se += expf(lg[j] - m);
    lse[0] = m + logf(se);
  }
  __syncthreads();
  if (tid < 28) out[b * 28 + tid] = lg[tid] - lse[0];
}

// ---------------------------------------------------------------------------
extern "C" void kernel_launch(void* const* d_in, const int* in_sizes, int n_in,
                              void* d_out, int out_size, void* d_ws, size_t ws_size,
                              hipStream_t stream) {
  (void)in_sizes; (void)n_in; (void)out_size; (void)ws_size;
  const float* x   = (const float*)d_in[0];
  const float* qst = (const float*)d_in[1];
  const float* g1w = (const float*)d_in[2];
  const float* g1b = (const float*)d_in[3];
  const float* g2w = (const float*)d_in[4];
  const float* g2b = (const float*)d_in[5];
  const float* g3w = (const float*)d_in[6];
  const float* g3b = (const float*)d_in[7];
  const float* g4w = (const float*)d_in[8];
  const float* g4b = (const float*)d_in[9];
  const float* f1w = (const float*)d_in[10];
  const float* f1b = (const float*)d_in[11];
  const float* f2w = (const float*)d_in[12];
  const float* f2b = (const float*)d_in[13];
  const float* f3w = (const float*)d_in[14];
  const float* f3b = (const float*)d_in[15];
  float* out = (float*)d_out;

  float*  Ap   = (float*)d_ws;
  float*  C    = Ap + 4096 * 256;
  bf16_t* Wt   = (bf16_t*)(C + 4096 * 256);
  float*  part = (float*)((char*)Wt + 3 * 65536 * sizeof(bf16_t));

  rn_prep_kernel<<<256 + 48, 256, 0, stream>>>(
      x, qst, g1w, g1b, g2w, g3w, g4w, Ap, C, Wt);
  rn_main_kernel<<<4096, 256, 0, stream>>>(Ap, C, Wt, g2b, g3b, g4b, part);
  rn_f_kernel<<<64, 256, 0, stream>>>(part, f1w, f1b, f2w, f2b, f3w, f3b, out);
}

// Round 14
// 240.126 us; speedup vs baseline: 1.0233x; 1.0233x over previous
//
#include <hip/hip_runtime.h>

typedef __bf16 bf16_t;
typedef __bf16 bf16x8 __attribute__((ext_vector_type(8)));
typedef __bf16 bf16x4 __attribute__((ext_vector_type(4)));
typedef float  f32x4  __attribute__((ext_vector_type(4)));

// ---------------------------------------------------------------------------
// Workspace layout (floats unless noted):
//   Ap : [64][16384] f32  xf@W1[0:26] in h-FRAGMENT-LINEAR order:
//        slot ((jt*8+it)*64 + q*16 + r)*8 + e = A[b][jt*16+r][it*32+q*8+e]
//   C  : [4096][256] f32  (xf @ W1[26:52] + qst @ W1[52:180] + b1)
//   Wt : 3 x [256][256] bf16 in MFMA A-fragment layout:
//        [mat][tile16(no>>4)][ks(k>>5)][lane(q*16+r)][e]
//   part : [2048][256] f32  per-block partial pair-sums
//
// h in LDS (single 128-row buffer pair): element (m,k), m = mt*16+r
// (mt 0..7: mt<4 = i0 rows, mt>=4 = i1 rows), k = ks*32+q*8+e ->
// slot ((mt*8+ks)*64 + q*16 + r)*8 + e.  All LDS ops lane-contiguous,
// zero bank conflicts by construction.
//
// Round 14: amortize the per-block fixed tax (r12's accounting: inner-loop
// pipe is ~saturated; the ~60% idle is build/epilogue/reduce/barrier-drain
// tax paid once per block, 16 blocks/CU).  M=128 per block (i-pair):
// 2x MFMA work per tax payment; one Ap read serves both i-values.
// Ping-pong hA/hB = 2 x 64 KB = 128 KB LDS -> 1 block/CU, 1 wave/SIMD,
// register budget 512 -> acc 128 + hf 32 + wf 16 + misc fits with ~300
// regs of scheduler slack (r13's spill lesson: do NOT pin W in registers
// at a tight budget; stream it and let the compiler pipeline).
// Skeleton unchanged from r12 (proven +14us): 3 barriers, ping-pong,
// Ap-coalesced build, setprio, XCD swizzle, partial stores.
// Race audit: build->hA |bar| L0 rd hA wr hB |bar| L1 rd hB wr hA |bar|
// L2 rd hA -> disjoint read/write sets between barriers; barriers uniform.
// ---------------------------------------------------------------------------

// ---------------- prep: Ap, C, weight fragment-relayout ---------------------
__global__ __launch_bounds__(256) void rn_prep_kernel(
    const float* __restrict__ x, const float* __restrict__ qst,
    const float* __restrict__ g1w, const float* __restrict__ g1b,
    const float* __restrict__ g2w, const float* __restrict__ g3w,
    const float* __restrict__ g4w,
    float* __restrict__ Ap, float* __restrict__ C,
    bf16_t* __restrict__ Wt)
{
  __shared__ float T[64][65];   // transpose tile (only used by that branch)
  int blk = blockIdx.x;
  int n   = threadIdx.x;  // 0..255
  if (blk < 256) {
    // block = (b, jg): rows jg*16 .. jg*16+15 of batch b; thread = output col n
    int b  = blk >> 2;
    int jg = (blk & 3) * 16;
    float accQ = g1b[n];
    const float* qb = qst + b * 128;
    #pragma unroll 8
    for (int qi = 0; qi < 128; ++qi)
      accQ += qb[qi] * g1w[(52 + qi) * 256 + n];

    float w24 = g1w[24 * 256 + n], w25 = g1w[25 * 256 + n];
    float w50 = g1w[50 * 256 + n], w51 = g1w[51 * 256 + n];
    float accA[16], accC[16];
    #pragma unroll
    for (int t = 0; t < 16; ++t) {
      int j = jg + t;
      // faithful to (a/d - d/2)/(d/2.0) float arithmetic, d=8 (exact pow2 ops)
      float cx = ((float)j * 0.125f - 4.0f) * 0.25f;
      float cy = ((float)(j & 7) - 4.0f) * 0.25f;
      accA[t] = cx * w24 + cy * w25;
      accC[t] = accQ + cx * w50 + cy * w51;
    }
    for (int c = 0; c < 24; ++c) {
      float wa = g1w[c * 256 + n];
      float wc = g1w[(26 + c) * 256 + n];
      const float* xc = x + (b * 24 + c) * 64 + jg;
      #pragma unroll
      for (int t = 0; t < 16; ++t) {
        float xv = xc[t];   // uniform per thread -> scalar load
        accA[t] += xv * wa;
        accC[t] += xv * wc;
      }
    }
    // A in fragment-linear order: j = jt*16 + t (jt = blk&3, r = t), k = n.
    int jt = blk & 3;
    int itA = n >> 5, qA = (n >> 3) & 3, eA = n & 7;
    int baseA = b * 16384 + (jt * 8 + itA) * 512 + qA * 128 + eA;
    #pragma unroll
    for (int t = 0; t < 16; ++t) {
      Ap[baseA + t * 8] = accA[t];
      C[(b * 64 + jg + t) * 256 + n] = accC[t];
    }
  } else {
    // LDS-tiled transpose: g2/g3/g4 [in(k)][out(no)] f32 -> bf16 fragment
    // layout: element (no,k) -> [(no>>4)*8 + (k>>5)][((k>>3)&3)*16 + (no&15)][k&7]
    int t   = blk - 256;
    int mat = t >> 4;                 // 0..2
    int tl  = t & 15;                 // 4x4 tiles of 64x64
    int kt  = (tl & 3) * 64;
    int nt_ = (tl >> 2) * 64;
    const float* W = (mat == 0) ? g2w : (mat == 1 ? g3w : g4w);
    int lane = n & 63, w = n >> 6;
    #pragma unroll
    for (int it = 0; it < 16; ++it) {
      int kl = w * 16 + it;
      T[kl][lane] = W[(kt + kl) * 256 + nt_ + lane];   // coalesced 256B/wave
    }
    __syncthreads();
    #pragma unroll
    for (int it = 0; it < 16; ++it) {
      int nl  = w * 16 + it;
      int no  = nt_ + nl;     // output-neuron index
      int k   = kt + lane;    // input index
      int tile = no >> 4, rr = no & 15;
      int ksI  = k >> 5,  qI = (k >> 3) & 3, e = k & 7;
      int idx  = ((tile * 8 + ksI) * 64 + qI * 16 + rr) * 8 + e;
      Wt[mat * 65536 + idx] = (bf16_t)T[lane][nl];
    }
  }
}

// ---------------- main fused g-MLP (layers 2..4) + pair partial-sum --------
// one block per (b, i-pair): M = 128 rows (2 i x 64 j), N = K = 256, 4 waves.
// Wave w owns n-rows [w*64, w*64+64) (nt=0..3) and ALL 128 m-rows (mt=0..7).
// Per ks: 4 wf global (1 KB coalesced) + 8 hf LDS -> 32 MFMA.
// Ping-pong: build->hA; L0 rd hA wr hB; L1 rd hB wr hA; L2 rd hA -> store.
// 128 KB LDS -> 1 block/CU, 1 wave/SIMD, 512-reg budget (no spill pressure).
__global__ __launch_bounds__(256, 1) void rn_main_kernel(
    const float* __restrict__ Ap, const float* __restrict__ C,
    const bf16_t* __restrict__ Wt,
    const float* __restrict__ g2b, const float* __restrict__ g3b,
    const float* __restrict__ g4b,
    float* __restrict__ part)
{
  __shared__ bf16_t hA[32768];   // 64 KB: [chunk=mt*8+ks][lane][8], mt 0..7
  __shared__ bf16_t hB[32768];   // 64 KB

  int tid  = threadIdx.x;
  int bx0  = blockIdx.x;
  // bijective XCD swizzle (2048 % 8 == 0): 256 consecutive work-units per
  // XCD -> the 32 blocks sharing a batch b stay on one XCD's L2
  int bx   = (bx0 & 7) * 256 + (bx0 >> 3);
  int b    = bx >> 5;          // batch
  int ip   = bx & 31;          // i-pair: i = 2*ip, 2*ip+1
  int lane = tid & 63;
  int wave = tid >> 6;
  int r    = lane & 15;        // 16-dim index within MFMA tile
  int q    = lane >> 4;        // quad: k-run selector / D-row group

  // ---- build h rows into hA (fragment-linear, both i-values) ----
  // wave w builds chunks mt=w (i0 rows) and mt=4+w (i1 rows); one Ap read
  // (lane-contiguous) serves both; C rows are cheap broadcasts.
  {
    const float* Apb = Ap + (size_t)b * 16384 + wave * 4096;
    const float* Cr  = C + ((size_t)b * 64 + ip * 2) * 256;
    #pragma unroll
    for (int it = 0; it < 8; ++it) {
      int k0 = it * 32 + q * 8;
      const float4 a0  = *(const float4*)(Apb + it * 512 + lane * 8);
      const float4 a1  = *(const float4*)(Apb + it * 512 + lane * 8 + 4);
      const float4 c00 = *(const float4*)(Cr + k0);
      const float4 c01 = *(const float4*)(Cr + k0 + 4);
      const float4 c10 = *(const float4*)(Cr + 256 + k0);
      const float4 c11 = *(const float4*)(Cr + 256 + k0 + 4);
      bf16x8 v0, v1;
      v0[0] = (bf16_t)fmaxf(a0.x + c00.x, 0.f);
      v0[1] = (bf16_t)fmaxf(a0.y + c00.y, 0.f);
      v0[2] = (bf16_t)fmaxf(a0.z + c00.z, 0.f);
      v0[3] = (bf16_t)fmaxf(a0.w + c00.w, 0.f);
      v0[4] = (bf16_t)fmaxf(a1.x + c01.x, 0.f);
      v0[5] = (bf16_t)fmaxf(a1.y + c01.y, 0.f);
      v0[6] = (bf16_t)fmaxf(a1.z + c01.z, 0.f);
      v0[7] = (bf16_t)fmaxf(a1.w + c01.w, 0.f);
      v1[0] = (bf16_t)fmaxf(a0.x + c10.x, 0.f);
      v1[1] = (bf16_t)fmaxf(a0.y + c10.y, 0.f);
      v1[2] = (bf16_t)fmaxf(a0.z + c10.z, 0.f);
      v1[3] = (bf16_t)fmaxf(a0.w + c10.w, 0.f);
      v1[4] = (bf16_t)fmaxf(a1.x + c11.x, 0.f);
      v1[5] = (bf16_t)fmaxf(a1.y + c11.y, 0.f);
      v1[6] = (bf16_t)fmaxf(a1.z + c11.z, 0.f);
      v1[7] = (bf16_t)fmaxf(a1.w + c11.w, 0.f);
      *(bf16x8*)&hA[((wave * 8 + it) * 64 + lane) * 8] = v0;         // mt = w
      *(bf16x8*)&hA[(((4 + wave) * 8 + it) * 64 + lane) * 8] = v1;   // mt = 4+w
    }
  }
  __syncthreads();             // hA complete

  #pragma unroll
  for (int L = 0; L < 3; ++L) {
    const bf16_t* hs = (L == 1) ? hB : hA;   // compile-time under unroll
    bf16_t*       hd = (L == 0) ? hB : hA;
    const bf16_t* Wl   = Wt + L * 65536 + wave * 16384;
    const float*  bias = (L == 0) ? g2b : (L == 1) ? g3b : g4b;

    f32x4 acc[4][8];           // [nt][mt]
    #pragma unroll
    for (int nt = 0; nt < 4; ++nt)
      #pragma unroll
      for (int mt = 0; mt < 8; ++mt)
        #pragma unroll
        for (int e = 0; e < 4; ++e) acc[nt][mt][e] = 0.f;

    #pragma unroll
    for (int ks = 0; ks < 8; ++ks) {
      bf16x8 wf[4], hf[8];
      #pragma unroll
      for (int nt = 0; nt < 4; ++nt)
        wf[nt] = *(const bf16x8*)&Wl[((nt * 8 + ks) * 64 + lane) * 8];
      #pragma unroll
      for (int mt = 0; mt < 8; ++mt)
        hf[mt] = *(const bf16x8*)&hs[((mt * 8 + ks) * 64 + lane) * 8];
      __builtin_amdgcn_s_setprio(1);
      #pragma unroll
      for (int nt = 0; nt < 4; ++nt)
        #pragma unroll
        for (int mt = 0; mt < 8; ++mt)
          acc[nt][mt] = __builtin_amdgcn_mfma_f32_16x16x32_bf16(
              wf[nt], hf[mt], acc[nt][mt], 0, 0, 0);
      __builtin_amdgcn_s_setprio(0);
    }
    // NO barrier here: reads were from hs, writes go to hd (disjoint).

    if (L < 2) {
      // D value (nt,mt,e): n = wave*64+nt*16+q*4+e (next layer's k),
      // m = mt*16+r.  Fragment-linear write into hd.
      #pragma unroll
      for (int nt = 0; nt < 4; ++nt) {
        int k0  = wave * 64 + nt * 16 + q * 4;
        float4 bv = *(const float4*)&bias[k0];
        int ks_ = k0 >> 5, rem = k0 & 31;
        int qp  = rem >> 3, e0 = rem & 7;     // e0 in {0,4}
        #pragma unroll
        for (int mt = 0; mt < 8; ++mt) {
          bf16x4 v;
          v[0] = (bf16_t)fmaxf(acc[nt][mt][0] + bv.x, 0.f);
          v[1] = (bf16_t)fmaxf(acc[nt][mt][1] + bv.y, 0.f);
          v[2] = (bf16_t)fmaxf(acc[nt][mt][2] + bv.z, 0.f);
          v[3] = (bf16_t)fmaxf(acc[nt][mt][3] + bv.w, 0.f);
          int off = ((mt * 8 + ks_) * 64 + qp * 16 + r) * 8 + e0;
          *(bf16x4*)&hd[off] = v;
        }
      }
      __syncthreads();         // hd complete before next layer reads it
    } else {
      // last layer: bias+relu fp32, sum over all 128 m-rows (both i-values
      // contribute to xg[b]), then plain float4 partial store (no atomics).
      #pragma unroll
      for (int nt = 0; nt < 4; ++nt) {
        int k0 = wave * 64 + nt * 16 + q * 4;
        float4 bv = *(const float4*)&bias[k0];
        float p0 = 0.f, p1 = 0.f, p2 = 0.f, p3 = 0.f;
        #pragma unroll
        for (int mt = 0; mt < 8; ++mt) {
          p0 += fmaxf(acc[nt][mt][0] + bv.x, 0.f);
          p1 += fmaxf(acc[nt][mt][1] + bv.y, 0.f);
          p2 += fmaxf(acc[nt][mt][2] + bv.z, 0.f);
          p3 += fmaxf(acc[nt][mt][3] + bv.w, 0.f);
        }
        #pragma unroll
        for (int d = 1; d < 16; d <<= 1) {
          p0 += __shfl_xor(p0, d, 64);
          p1 += __shfl_xor(p1, d, 64);
          p2 += __shfl_xor(p2, d, 64);
          p3 += __shfl_xor(p3, d, 64);
        }
        if (r == 0) {
          float4 pv = make_float4(p0, p1, p2, p3);
          *(float4*)&part[(size_t)bx * 256 + k0] = pv;
        }
      }
    }
  }
}

// ---------------- partial reduce + f-MLP + log_softmax (tiny, fp32) --------
__global__ __launch_bounds__(256) void rn_f_kernel(
    const float* __restrict__ part,
    const float* __restrict__ f1w, const float* __restrict__ f1b,
    const float* __restrict__ f2w, const float* __restrict__ f2b,
    const float* __restrict__ f3w, const float* __restrict__ f3b,
    float* __restrict__ out)
{
  __shared__ float xs[256], t1[256], t2[256], lg[28], lse[1];
  int b = blockIdx.x, tid = threadIdx.x;
  // reduce the 32 per-ip partials of batch b (coalesced 1 KB/wave per iter)
  float s = 0.f;
  const float* pb = part + (size_t)b * 32 * 256;
  #pragma unroll 8
  for (int i = 0; i < 32; ++i) s += pb[i * 256 + tid];
  xs[tid] = s;
  __syncthreads();
  float acc = f1b[tid];
  for (int k = 0; k < 256; ++k) acc += xs[k] * f1w[k * 256 + tid];
  t1[tid] = fmaxf(acc, 0.f);
  __syncthreads();
  acc = f2b[tid];
  for (int k = 0; k < 256; ++k) acc += t1[k] * f2w[k * 256 + tid];
  t2[tid] = fmaxf(acc, 0.f);
  __syncthreads();
  if (tid < 28) {
    float a2 = f3b[tid];
    for (int k = 0; k < 256; ++k) a2 += t2[k] * f3w[k * 28 + tid];
    lg[tid] = a2;
  }
  __syncthreads();
  if (tid == 0) {
    float m = lg[0];
    for (int j = 1; j < 28; ++j) m = fmaxf(m, lg[j]);
    float se = 0.f;
    for (int j = 0; j < 28; ++j) se += expf(lg[j] - m);
    lse[0] = m + logf(se);
  }
  __syncthreads();
  if (tid < 28) out[b * 28 + tid] = lg[tid] - lse[0];
}

// ---------------------------------------------------------------------------
extern "C" void kernel_launch(void* const* d_in, const int* in_sizes, int n_in,
                              void* d_out, int out_size, void* d_ws, size_t ws_size,
                              hipStream_t stream) {
  (void)in_sizes; (void)n_in; (void)out_size; (void)ws_size;
  const float* x   = (const float*)d_in[0];
  const float* qst = (const float*)d_in[1];
  const float* g1w = (const float*)d_in[2];
  const float* g1b = (const float*)d_in[3];
  const float* g2w = (const float*)d_in[4];
  const float* g2b = (const float*)d_in[5];
  const float* g3w = (const float*)d_in[6];
  const float* g3b = (const float*)d_in[7];
  const float* g4w = (const float*)d_in[8];
  const float* g4b = (const float*)d_in[9];
  const float* f1w = (const float*)d_in[10];
  const float* f1b = (const float*)d_in[11];
  const float* f2w = (const float*)d_in[12];
  const float* f2b = (const float*)d_in[13];
  const float* f3w = (const float*)d_in[14];
  const float* f3b = (const float*)d_in[15];
  float* out = (float*)d_out;

  float*  Ap   = (float*)d_ws;
  float*  C    = Ap + 4096 * 256;
  bf16_t* Wt   = (bf16_t*)(C + 4096 * 256);
  float*  part = (float*)((char*)Wt + 3 * 65536 * sizeof(bf16_t));

  rn_prep_kernel<<<256 + 48, 256, 0, stream>>>(
      x, qst, g1w, g1b, g2w, g3w, g4w, Ap, C, Wt);
  rn_main_kernel<<<2048, 256, 0, stream>>>(Ap, C, Wt, g2b, g3b, g4b, part);
  rn_f_kernel<<<64, 256, 0, stream>>>(part, f1w, f1b, f2w, f2b, f3w, f3b, out);
}

// Round 15
// 221.931 us; speedup vs baseline: 1.1072x; 1.0820x over previous
//
#include <hip/hip_runtime.h>

typedef __bf16 bf16_t;
typedef __bf16 bf16x8 __attribute__((ext_vector_type(8)));
typedef __bf16 bf16x4 __attribute__((ext_vector_type(4)));
typedef float  f32x4  __attribute__((ext_vector_type(4)));

// ---------------------------------------------------------------------------
// Workspace layout (floats unless noted):
//   Ap : [64][16384] f32  xf@W1[0:26] in h-FRAGMENT-LINEAR order:
//        slot ((jt*8+it)*64 + q*16 + r)*8 + e = A[b][jt*16+r][it*32+q*8+e]
//   C  : [4096][256] f32  (xf @ W1[26:52] + qst @ W1[52:180] + b1)
//   Wt : 3 x [256][256] bf16 in MFMA A-fragment layout:
//        [mat][tile16(no>>4)][ks(k>>5)][lane(q*16+r)][e]
//   part : [4096][256] f32  per-block partial pair-sums
//
// h in LDS: B-fragment-linear  h[chunk = mt*8+ks][lane = q*16+r][e]
//   <-> h[m = mt*16+r][k = ks*32+q*8+e]  -> all LDS ops lane-contiguous,
//   zero bank conflicts by construction.
//
// Round 15 = r12 (best: 123.5us main / 229.4 total, MfmaUtil 36.4) + three
// surgical changes:
//  1. SOFT BARRIERS: {s_waitcnt lgkmcnt(0); s_barrier; sched_barrier(0)}
//     instead of __syncthreads.  All inter-wave dependencies are LDS
//     (hd ds_writes), covered by lgkmcnt(0).  __syncthreads' vmcnt(0)
//     drain killed every in-flight global load at each of the 3 layer
//     boundaries -- each layer restarted its W stream cold.
//  2. wf-ks0 PREFETCH: the next layer's first 4 W-fragment loads issue
//     BEFORE the soft barrier and stay in flight across it (the T4
//     counted-vmcnt mechanism in miniature); after the barrier the first
//     MFMA burst waits only on LDS hf reads.
//  3. f-kernel ILP: 4-way accumulator splits for the three 256-deep
//     serial FMA chains and the part reduce (was pure latency-bound).
// Race audit unchanged from r12: build->hA |bar| L0 rd hA wr hB |bar|
// L1 rd hB wr hA |bar| L2 rd hA; disjoint LDS read/write sets between
// barriers; barriers block-uniform.  Spill check: WRITE_SIZE ~4 MB.
// ---------------------------------------------------------------------------

// ---------------- prep: Ap, C, weight fragment-relayout ---------------------
__global__ __launch_bounds__(256) void rn_prep_kernel(
    const float* __restrict__ x, const float* __restrict__ qst,
    const float* __restrict__ g1w, const float* __restrict__ g1b,
    const float* __restrict__ g2w, const float* __restrict__ g3w,
    const float* __restrict__ g4w,
    float* __restrict__ Ap, float* __restrict__ C,
    bf16_t* __restrict__ Wt)
{
  __shared__ float T[64][65];   // transpose tile (only used by that branch)
  int blk = blockIdx.x;
  int n   = threadIdx.x;  // 0..255
  if (blk < 256) {
    // block = (b, jg): rows jg*16 .. jg*16+15 of batch b; thread = output col n
    int b  = blk >> 2;
    int jg = (blk & 3) * 16;
    float accQ = g1b[n];
    const float* qb = qst + b * 128;
    #pragma unroll 8
    for (int qi = 0; qi < 128; ++qi)
      accQ += qb[qi] * g1w[(52 + qi) * 256 + n];

    float w24 = g1w[24 * 256 + n], w25 = g1w[25 * 256 + n];
    float w50 = g1w[50 * 256 + n], w51 = g1w[51 * 256 + n];
    float accA[16], accC[16];
    #pragma unroll
    for (int t = 0; t < 16; ++t) {
      int j = jg + t;
      // faithful to (a/d - d/2)/(d/2.0) float arithmetic, d=8 (exact pow2 ops)
      float cx = ((float)j * 0.125f - 4.0f) * 0.25f;
      float cy = ((float)(j & 7) - 4.0f) * 0.25f;
      accA[t] = cx * w24 + cy * w25;
      accC[t] = accQ + cx * w50 + cy * w51;
    }
    for (int c = 0; c < 24; ++c) {
      float wa = g1w[c * 256 + n];
      float wc = g1w[(26 + c) * 256 + n];
      const float* xc = x + (b * 24 + c) * 64 + jg;
      #pragma unroll
      for (int t = 0; t < 16; ++t) {
        float xv = xc[t];   // uniform per thread -> scalar load
        accA[t] += xv * wa;
        accC[t] += xv * wc;
      }
    }
    // A in fragment-linear order: j = jt*16 + t (jt = blk&3, r = t), k = n.
    int jt = blk & 3;
    int itA = n >> 5, qA = (n >> 3) & 3, eA = n & 7;
    int baseA = b * 16384 + (jt * 8 + itA) * 512 + qA * 128 + eA;
    #pragma unroll
    for (int t = 0; t < 16; ++t) {
      Ap[baseA + t * 8] = accA[t];
      C[(b * 64 + jg + t) * 256 + n] = accC[t];
    }
  } else {
    // LDS-tiled transpose: g2/g3/g4 [in(k)][out(no)] f32 -> bf16 fragment
    // layout: element (no,k) -> [(no>>4)*8 + (k>>5)][((k>>3)&3)*16 + (no&15)][k&7]
    int t   = blk - 256;
    int mat = t >> 4;                 // 0..2
    int tl  = t & 15;                 // 4x4 tiles of 64x64
    int kt  = (tl & 3) * 64;
    int nt_ = (tl >> 2) * 64;
    const float* W = (mat == 0) ? g2w : (mat == 1 ? g3w : g4w);
    int lane = n & 63, w = n >> 6;
    #pragma unroll
    for (int it = 0; it < 16; ++it) {
      int kl = w * 16 + it;
      T[kl][lane] = W[(kt + kl) * 256 + nt_ + lane];   // coalesced 256B/wave
    }
    __syncthreads();
    #pragma unroll
    for (int it = 0; it < 16; ++it) {
      int nl  = w * 16 + it;
      int no  = nt_ + nl;     // output-neuron index
      int k   = kt + lane;    // input index
      int tile = no >> 4, rr = no & 15;
      int ksI  = k >> 5,  qI = (k >> 3) & 3, e = k & 7;
      int idx  = ((tile * 8 + ksI) * 64 + qI * 16 + rr) * 8 + e;
      Wt[mat * 65536 + idx] = (bf16_t)T[lane][nl];
    }
  }
}

// soft barrier: LDS visibility only; global loads stay in flight across it.
#define SOFTBAR()                                            \
  do {                                                       \
    asm volatile("s_waitcnt lgkmcnt(0)" ::: "memory");       \
    __builtin_amdgcn_s_barrier();                            \
    __builtin_amdgcn_sched_barrier(0);                       \
  } while (0)

// ---------------- main fused g-MLP (layers 2..4) + pair partial-sum --------
// one block per (b, i): M = 64 rows, N = K = 256, 4 waves.
// Wave w owns n-rows [w*64, w*64+64) (nt=0..3) and all 64 m-rows (mt=0..3).
// Per ks: 4 wf global (1 KB coalesced, L2-shared) + 4 hf LDS -> 16 MFMA.
// Ping-pong: build->hA; L0 rd hA wr hB; L1 rd hB wr hA; L2 rd hA -> store.
// Soft barriers + cross-barrier wf-ks0 prefetch keep the W stream warm.
__global__ __launch_bounds__(256, 2) void rn_main_kernel(
    const float* __restrict__ Ap, const float* __restrict__ C,
    const bf16_t* __restrict__ Wt,
    const float* __restrict__ g2b, const float* __restrict__ g3b,
    const float* __restrict__ g4b,
    float* __restrict__ part)
{
  __shared__ bf16_t hA[16384];   // 32 KB: [chunk=mt*8+ks][lane][8]
  __shared__ bf16_t hB[16384];   // 32 KB

  int tid  = threadIdx.x;
  int bx0  = blockIdx.x;
  // bijective XCD swizzle (4096 % 8 == 0): 512 consecutive work-units per
  // XCD -> the 64 blocks sharing a batch b stay on one XCD's L2
  int bx   = (bx0 & 7) * 512 + (bx0 >> 3);
  int b    = bx >> 6;          // batch
  int i    = bx & 63;          // i-object
  int lane = tid & 63;
  int wave = tid >> 6;
  int r    = lane & 15;        // 16-dim index within MFMA tile
  int q    = lane >> 4;        // quad: k-run selector / D-row group

  bf16x8 wf0[4];               // next layer's ks=0 W fragments (in flight
                               // across the soft barrier)

#define PREFETCH_WF0(LL)                                                    \
  {                                                                         \
    const bf16_t* Wn = Wt + (LL) * 65536 + wave * 16384;                    \
    _Pragma("unroll")                                                       \
    for (int nt = 0; nt < 4; ++nt)                                          \
      wf0[nt] = *(const bf16x8*)&Wn[(nt * 8 * 64 + lane) * 8];              \
  }

  // ---- build h rows into hA (fragment-linear) ----
  // wave w builds chunks (mt=w, ks=it).  Ap is pre-arranged so the A read is
  // lane-contiguous; C row i is a cheap broadcast.
  {
    const float* Apb = Ap + (size_t)b * 16384 + wave * 4096;
    const float* Cr  = C + ((size_t)b * 64 + i) * 256;
    #pragma unroll
    for (int it = 0; it < 8; ++it) {
      int k0 = it * 32 + q * 8;
      const float4 a0 = *(const float4*)(Apb + it * 512 + lane * 8);
      const float4 a1 = *(const float4*)(Apb + it * 512 + lane * 8 + 4);
      const float4 c0 = *(const float4*)(Cr + k0);
      const float4 c1 = *(const float4*)(Cr + k0 + 4);
      bf16x8 v;
      v[0] = (bf16_t)fmaxf(a0.x + c0.x, 0.f);
      v[1] = (bf16_t)fmaxf(a0.y + c0.y, 0.f);
      v[2] = (bf16_t)fmaxf(a0.z + c0.z, 0.f);
      v[3] = (bf16_t)fmaxf(a0.w + c0.w, 0.f);
      v[4] = (bf16_t)fmaxf(a1.x + c1.x, 0.f);
      v[5] = (bf16_t)fmaxf(a1.y + c1.y, 0.f);
      v[6] = (bf16_t)fmaxf(a1.z + c1.z, 0.f);
      v[7] = (bf16_t)fmaxf(a1.w + c1.w, 0.f);
      *(bf16x8*)&hA[((wave * 8 + it) * 64 + lane) * 8] = v;
    }
  }
  PREFETCH_WF0(0)
  SOFTBAR();                   // hA visible; wf0 loads still in flight

  #pragma unroll
  for (int L = 0; L < 3; ++L) {
    const bf16_t* hs = (L == 1) ? hB : hA;   // compile-time under unroll
    bf16_t*       hd = (L == 0) ? hB : hA;
    const bf16_t* Wl   = Wt + L * 65536 + wave * 16384;
    const float*  bias = (L == 0) ? g2b : (L == 1) ? g3b : g4b;

    f32x4 acc[4][4];           // [nt][mt]
    #pragma unroll
    for (int nt = 0; nt < 4; ++nt)
      #pragma unroll
      for (int mt = 0; mt < 4; ++mt)
        #pragma unroll
        for (int e = 0; e < 4; ++e) acc[nt][mt][e] = 0.f;

    #pragma unroll
    for (int ks = 0; ks < 8; ++ks) {
      bf16x8 wf[4], hf[4];
      #pragma unroll
      for (int nt = 0; nt < 4; ++nt)
        wf[nt] = (ks == 0) ? wf0[nt]
                 : *(const bf16x8*)&Wl[((nt * 8 + ks) * 64 + lane) * 8];
      #pragma unroll
      for (int mt = 0; mt < 4; ++mt)
        hf[mt] = *(const bf16x8*)&hs[((mt * 8 + ks) * 64 + lane) * 8];
      __builtin_amdgcn_s_setprio(1);
      #pragma unroll
      for (int nt = 0; nt < 4; ++nt)
        #pragma unroll
        for (int mt = 0; mt < 4; ++mt)
          acc[nt][mt] = __builtin_amdgcn_mfma_f32_16x16x32_bf16(
              wf[nt], hf[mt], acc[nt][mt], 0, 0, 0);
      __builtin_amdgcn_s_setprio(0);
    }
    // NO barrier here: reads were from hs, writes go to hd (disjoint).

    if (L < 2) {
      // D value (nt,mt,e): n = wave*64+nt*16+q*4+e (next layer's k),
      // m = mt*16+r.  Fragment-linear write into hd.
      #pragma unroll
      for (int nt = 0; nt < 4; ++nt) {
        int k0  = wave * 64 + nt * 16 + q * 4;
        float4 bv = *(const float4*)&bias[k0];
        int ks_ = k0 >> 5, rem = k0 & 31;
        int qp  = rem >> 3, e0 = rem & 7;     // e0 in {0,4}
        #pragma unroll
        for (int mt = 0; mt < 4; ++mt) {
          bf16x4 v;
          v[0] = (bf16_t)fmaxf(acc[nt][mt][0] + bv.x, 0.f);
          v[1] = (bf16_t)fmaxf(acc[nt][mt][1] + bv.y, 0.f);
          v[2] = (bf16_t)fmaxf(acc[nt][mt][2] + bv.z, 0.f);
          v[3] = (bf16_t)fmaxf(acc[nt][mt][3] + bv.w, 0.f);
          int off = ((mt * 8 + ks_) * 64 + qp * 16 + r) * 8 + e0;
          *(bf16x4*)&hd[off] = v;
        }
      }
      // next layer's ks0 W loads issue here and stay in flight across the
      // soft barrier (no vmcnt drain).
      if (L == 0) PREFETCH_WF0(1)
      else        PREFETCH_WF0(2)
      SOFTBAR();               // hd visible before next layer reads it
    } else {
      // last layer: bias+relu fp32, sum over the 64 m-rows (mt in-register,
      // then the 16 r-lanes), plain float4 partial store (no atomics).
      #pragma unroll
      for (int nt = 0; nt < 4; ++nt) {
        int k0 = wave * 64 + nt * 16 + q * 4;
        float4 bv = *(const float4*)&bias[k0];
        float p0 = 0.f, p1 = 0.f, p2 = 0.f, p3 = 0.f;
        #pragma unroll
        for (int mt = 0; mt < 4; ++mt) {
          p0 += fmaxf(acc[nt][mt][0] + bv.x, 0.f);
          p1 += fmaxf(acc[nt][mt][1] + bv.y, 0.f);
          p2 += fmaxf(acc[nt][mt][2] + bv.z, 0.f);
          p3 += fmaxf(acc[nt][mt][3] + bv.w, 0.f);
        }
        #pragma unroll
        for (int d = 1; d < 16; d <<= 1) {
          p0 += __shfl_xor(p0, d, 64);
          p1 += __shfl_xor(p1, d, 64);
          p2 += __shfl_xor(p2, d, 64);
          p3 += __shfl_xor(p3, d, 64);
        }
        if (r == 0) {
          float4 pv = make_float4(p0, p1, p2, p3);
          *(float4*)&part[(size_t)bx * 256 + k0] = pv;
        }
      }
    }
  }
#undef PREFETCH_WF0
}

// ---------------- partial reduce + f-MLP + log_softmax (tiny, fp32) --------
// 4-way accumulator splits break the 256-deep serial FMA dependency chains.
__global__ __launch_bounds__(256) void rn_f_kernel(
    const float* __restrict__ part,
    const float* __restrict__ f1w, const float* __restrict__ f1b,
    const float* __restrict__ f2w, const float* __restrict__ f2b,
    const float* __restrict__ f3w, const float* __restrict__ f3b,
    float* __restrict__ out)
{
  __shared__ float xs[256], t1[256], t2[256], lg[28], lse[1];
  int b = blockIdx.x, tid = threadIdx.x;
  // reduce the 64 per-i partials of batch b (coalesced 1 KB/wave per iter)
  {
    float s0 = 0.f, s1 = 0.f, s2 = 0.f, s3 = 0.f;
    const float* pb = part + (size_t)b * 64 * 256;
    #pragma unroll 4
    for (int i = 0; i < 64; i += 4) {
      s0 += pb[(i + 0) * 256 + tid];
      s1 += pb[(i + 1) * 256 + tid];
      s2 += pb[(i + 2) * 256 + tid];
      s3 += pb[(i + 3) * 256 + tid];
    }
    xs[tid] = (s0 + s1) + (s2 + s3);
  }
  __syncthreads();
  {
    float a0 = 0.f, a1 = 0.f, a2 = 0.f, a3 = 0.f;
    for (int k = 0; k < 256; k += 4) {
      a0 += xs[k + 0] * f1w[(k + 0) * 256 + tid];
      a1 += xs[k + 1] * f1w[(k + 1) * 256 + tid];
      a2 += xs[k + 2] * f1w[(k + 2) * 256 + tid];
      a3 += xs[k + 3] * f1w[(k + 3) * 256 + tid];
    }
    t1[tid] = fmaxf(f1b[tid] + (a0 + a1) + (a2 + a3), 0.f);
  }
  __syncthreads();
  {
    float a0 = 0.f, a1 = 0.f, a2 = 0.f, a3 = 0.f;
    for (int k = 0; k < 256; k += 4) {
      a0 += t1[k + 0] * f2w[(k + 0) * 256 + tid];
      a1 += t1[k + 1] * f2w[(k + 1) * 256 + tid];
      a2 += t1[k + 2] * f2w[(k + 2) * 256 + tid];
      a3 += t1[k + 3] * f2w[(k + 3) * 256 + tid];
    }
    t2[tid] = fmaxf(f2b[tid] + (a0 + a1) + (a2 + a3), 0.f);
  }
  __syncthreads();
  if (tid < 28) {
    float a0 = 0.f, a1 = 0.f, a2 = 0.f, a3 = 0.f;
    for (int k = 0; k < 256; k += 4) {
      a0 += t2[k + 0] * f3w[(k + 0) * 28 + tid];
      a1 += t2[k + 1] * f3w[(k + 1) * 28 + tid];
      a2 += t2[k + 2] * f3w[(k + 2) * 28 + tid];
      a3 += t2[k + 3] * f3w[(k + 3) * 28 + tid];
    }
    lg[tid] = f3b[tid] + (a0 + a1) + (a2 + a3);
  }
  __syncthreads();
  if (tid == 0) {
    float m = lg[0];
    for (int j = 1; j < 28; ++j) m = fmaxf(m, lg[j]);
    float se = 0.f;
    for (int j = 0; j < 28; ++j) se += expf(lg[j] - m);
    lse[0] = m + logf(se);
  }
  __syncthreads();
  if (tid < 28) out[b * 28 + tid] = lg[tid] - lse[0];
}

// ---------------------------------------------------------------------------
extern "C" void kernel_launch(void* const* d_in, const int* in_sizes, int n_in,
                              void* d_out, int out_size, void* d_ws, size_t ws_size,
                              hipStream_t stream) {
  (void)in_sizes; (void)n_in; (void)out_size; (void)ws_size;
  const float* x   = (const float*)d_in[0];
  const float* qst = (const float*)d_in[1];
  const float* g1w = (const float*)d_in[2];
  const float* g1b = (const float*)d_in[3];
  const float* g2w = (const float*)d_in[4];
  const float* g2b = (const float*)d_in[5];
  const float* g3w = (const float*)d_in[6];
  const float* g3b = (const float*)d_in[7];
  const float* g4w = (const float*)d_in[8];
  const float* g4b = (const float*)d_in[9];
  const float* f1w = (const float*)d_in[10];
  const float* f1b = (const float*)d_in[11];
  const float* f2w = (const float*)d_in[12];
  const float* f2b = (const float*)d_in[13];
  const float* f3w = (const float*)d_in[14];
  const float* f3b = (const float*)d_in[15];
  float* out = (float*)d_out;

  float*  Ap   = (float*)d_ws;
  float*  C    = Ap + 4096 * 256;
  bf16_t* Wt   = (bf16_t*)(C + 4096 * 256);
  float*  part = (float*)((char*)Wt + 3 * 65536 * sizeof(bf16_t));

  rn_prep_kernel<<<256 + 48, 256, 0, stream>>>(
      x, qst, g1w, g1b, g2w, g3w, g4w, Ap, C, Wt);
  rn_main_kernel<<<4096, 256, 0, stream>>>(Ap, C, Wt, g2b, g3b, g4b, part);
  rn_f_kernel<<<64, 256, 0, stream>>>(part, f1w, f1b, f2w, f2b, f3w, f3b, out);
}

// Round 17
// 220.688 us; speedup vs baseline: 1.1134x; 1.0056x over previous
//
#include <hip/hip_runtime.h>

typedef __bf16 bf16_t;
typedef __bf16 bf16x8 __attribute__((ext_vector_type(8)));
typedef __bf16 bf16x4 __attribute__((ext_vector_type(4)));
typedef float  f32x4  __attribute__((ext_vector_type(4)));

// ---------------------------------------------------------------------------
// Workspace layout (floats unless noted):
//   Ap : [64][16384] f32  xf@W1[0:26] in h-FRAGMENT-LINEAR order:
//        slot ((jt*8+it)*64 + q*16 + r)*8 + e = A[b][jt*16+r][it*32+q*8+e]
//   C  : [4096][256] f32  (xf @ W1[26:52] + qst @ W1[52:180] + b1)
//   Wt : 3 x [256][256] bf16 in MFMA A-fragment layout:
//        [mat][tile16(no>>4)][ks(k>>5)][lane(q*16+r)][e]
//   part : [4096][256] f32  per-block partial pair-sums
//
// h in LDS: B-fragment-linear  h[chunk = mt*8+ks][lane = q*16+r][e]
//   <-> h[m = mt*16+r][k = ks*32+q*8+e]  -> all LDS ops lane-contiguous,
//   zero bank conflicts by construction.
//
// Round 17 = r15 restored exactly (fp8 r16 failed accuracy 16.0 > 8.6 --
// per-layer e4m3 re-quantization compounds through the 4096-pair sum; no
// mixed fp8xbf16 MFMA exists, so fp8 is dead for this op) + ONE zero-risk
// change: 4-way ILP split of prep's 128-deep serial accQ FMA chain (the
// only remaining unexamined latency chain; same class of fix as r15's
// f-kernel split, which was worth ~6us).
// Main kernel is byte-identical to r15 (verified: 122.0us, MfmaUtil 36.7).
// ---------------------------------------------------------------------------

// ---------------- prep: Ap, C, weight fragment-relayout ---------------------
__global__ __launch_bounds__(256) void rn_prep_kernel(
    const float* __restrict__ x, const float* __restrict__ qst,
    const float* __restrict__ g1w, const float* __restrict__ g1b,
    const float* __restrict__ g2w, const float* __restrict__ g3w,
    const float* __restrict__ g4w,
    float* __restrict__ Ap, float* __restrict__ C,
    bf16_t* __restrict__ Wt)
{
  __shared__ float T[64][65];   // transpose tile (only used by that branch)
  int blk = blockIdx.x;
  int n   = threadIdx.x;  // 0..255
  if (blk < 256) {
    // block = (b, jg): rows jg*16 .. jg*16+15 of batch b; thread = output col n
    int b  = blk >> 2;
    int jg = (blk & 3) * 16;
    // 4-way split of the 128-deep qst dot-product chain (was latency-bound)
    float q0 = 0.f, q1 = 0.f, q2 = 0.f, q3 = 0.f;
    const float* qb = qst + b * 128;
    #pragma unroll 4
    for (int qi = 0; qi < 128; qi += 4) {
      q0 += qb[qi + 0] * g1w[(52 + qi + 0) * 256 + n];
      q1 += qb[qi + 1] * g1w[(52 + qi + 1) * 256 + n];
      q2 += qb[qi + 2] * g1w[(52 + qi + 2) * 256 + n];
      q3 += qb[qi + 3] * g1w[(52 + qi + 3) * 256 + n];
    }
    float accQ = g1b[n] + (q0 + q1) + (q2 + q3);

    float w24 = g1w[24 * 256 + n], w25 = g1w[25 * 256 + n];
    float w50 = g1w[50 * 256 + n], w51 = g1w[51 * 256 + n];
    float accA[16], accC[16];
    #pragma unroll
    for (int t = 0; t < 16; ++t) {
      int j = jg + t;
      // faithful to (a/d - d/2)/(d/2.0) float arithmetic, d=8 (exact pow2 ops)
      float cx = ((float)j * 0.125f - 4.0f) * 0.25f;
      float cy = ((float)(j & 7) - 4.0f) * 0.25f;
      accA[t] = cx * w24 + cy * w25;
      accC[t] = accQ + cx * w50 + cy * w51;
    }
    for (int c = 0; c < 24; ++c) {
      float wa = g1w[c * 256 + n];
      float wc = g1w[(26 + c) * 256 + n];
      const float* xc = x + (b * 24 + c) * 64 + jg;
      #pragma unroll
      for (int t = 0; t < 16; ++t) {
        float xv = xc[t];   // uniform per thread -> scalar load
        accA[t] += xv * wa;
        accC[t] += xv * wc;
      }
    }
    // A in fragment-linear order: j = jt*16 + t (jt = blk&3, r = t), k = n.
    int jt = blk & 3;
    int itA = n >> 5, qA = (n >> 3) & 3, eA = n & 7;
    int baseA = b * 16384 + (jt * 8 + itA) * 512 + qA * 128 + eA;
    #pragma unroll
    for (int t = 0; t < 16; ++t) {
      Ap[baseA + t * 8] = accA[t];
      C[(b * 64 + jg + t) * 256 + n] = accC[t];
    }
  } else {
    // LDS-tiled transpose: g2/g3/g4 [in(k)][out(no)] f32 -> bf16 fragment
    // layout: element (no,k) -> [(no>>4)*8 + (k>>5)][((k>>3)&3)*16 + (no&15)][k&7]
    int t   = blk - 256;
    int mat = t >> 4;                 // 0..2
    int tl  = t & 15;                 // 4x4 tiles of 64x64
    int kt  = (tl & 3) * 64;
    int nt_ = (tl >> 2) * 64;
    const float* W = (mat == 0) ? g2w : (mat == 1 ? g3w : g4w);
    int lane = n & 63, w = n >> 6;
    #pragma unroll
    for (int it = 0; it < 16; ++it) {
      int kl = w * 16 + it;
      T[kl][lane] = W[(kt + kl) * 256 + nt_ + lane];   // coalesced 256B/wave
    }
    __syncthreads();
    #pragma unroll
    for (int it = 0; it < 16; ++it) {
      int nl  = w * 16 + it;
      int no  = nt_ + nl;     // output-neuron index
      int k   = kt + lane;    // input index
      int tile = no >> 4, rr = no & 15;
      int ksI  = k >> 5,  qI = (k >> 3) & 3, e = k & 7;
      int idx  = ((tile * 8 + ksI) * 64 + qI * 16 + rr) * 8 + e;
      Wt[mat * 65536 + idx] = (bf16_t)T[lane][nl];
    }
  }
}

// soft barrier: LDS visibility only; global loads stay in flight across it.
#define SOFTBAR()                                            \
  do {                                                       \
    asm volatile("s_waitcnt lgkmcnt(0)" ::: "memory");       \
    __builtin_amdgcn_s_barrier();                            \
    __builtin_amdgcn_sched_barrier(0);                       \
  } while (0)

// ---------------- main fused g-MLP (layers 2..4) + pair partial-sum --------
// one block per (b, i): M = 64 rows, N = K = 256, 4 waves.
// Wave w owns n-rows [w*64, w*64+64) (nt=0..3) and all 64 m-rows (mt=0..3).
// Per ks: 4 wf global (1 KB coalesced, L2-shared) + 4 hf LDS -> 16 MFMA.
// Ping-pong: build->hA; L0 reads hA writes hB; L1 reads hB writes hA;
// L2 reads hA -> partial store.  Soft barriers + cross-barrier wf-ks0
// prefetch keep the W stream warm across layer boundaries.
__global__ __launch_bounds__(256, 2) void rn_main_kernel(
    const float* __restrict__ Ap, const float* __restrict__ C,
    const bf16_t* __restrict__ Wt,
    const float* __restrict__ g2b, const float* __restrict__ g3b,
    const float* __restrict__ g4b,
    float* __restrict__ part)
{
  __shared__ bf16_t hA[16384];   // 32 KB: [chunk=mt*8+ks][lane][8]
  __shared__ bf16_t hB[16384];   // 32 KB

  int tid  = threadIdx.x;
  int bx0  = blockIdx.x;
  // bijective XCD swizzle (4096 % 8 == 0): 512 consecutive work-units per
  // XCD -> the 64 blocks sharing a batch b stay on one XCD's L2
  int bx   = (bx0 & 7) * 512 + (bx0 >> 3);
  int b    = bx >> 6;          // batch
  int i    = bx & 63;          // i-object
  int lane = tid & 63;
  int wave = tid >> 6;
  int r    = lane & 15;        // 16-dim index within MFMA tile
  int q    = lane >> 4;        // quad: k-run selector / D-row group

  bf16x8 wf0[4];               // next layer's ks=0 W fragments (in flight
                               // across the soft barrier)

#define PREFETCH_WF0(LL)                                                    \
  {                                                                         \
    const bf16_t* Wn = Wt + (LL) * 65536 + wave * 16384;                    \
    _Pragma("unroll")                                                       \
    for (int nt = 0; nt < 4; ++nt)                                          \
      wf0[nt] = *(const bf16x8*)&Wn[(nt * 8 * 64 + lane) * 8];              \
  }

  // ---- build h rows into hA (fragment-linear) ----
  // wave w builds chunks (mt=w, ks=it).  Ap is pre-arranged so the A read is
  // lane-contiguous; C row i is a cheap broadcast.
  {
    const float* Apb = Ap + (size_t)b * 16384 + wave * 4096;
    const float* Cr  = C + ((size_t)b * 64 + i) * 256;
    #pragma unroll
    for (int it = 0; it < 8; ++it) {
      int k0 = it * 32 + q * 8;
      const float4 a0 = *(const float4*)(Apb + it * 512 + lane * 8);
      const float4 a1 = *(const float4*)(Apb + it * 512 + lane * 8 + 4);
      const float4 c0 = *(const float4*)(Cr + k0);
      const float4 c1 = *(const float4*)(Cr + k0 + 4);
      bf16x8 v;
      v[0] = (bf16_t)fmaxf(a0.x + c0.x, 0.f);
      v[1] = (bf16_t)fmaxf(a0.y + c0.y, 0.f);
      v[2] = (bf16_t)fmaxf(a0.z + c0.z, 0.f);
      v[3] = (bf16_t)fmaxf(a0.w + c0.w, 0.f);
      v[4] = (bf16_t)fmaxf(a1.x + c1.x, 0.f);
      v[5] = (bf16_t)fmaxf(a1.y + c1.y, 0.f);
      v[6] = (bf16_t)fmaxf(a1.z + c1.z, 0.f);
      v[7] = (bf16_t)fmaxf(a1.w + c1.w, 0.f);
      *(bf16x8*)&hA[((wave * 8 + it) * 64 + lane) * 8] = v;
    }
  }
  PREFETCH_WF0(0)
  SOFTBAR();                   // hA visible; wf0 loads still in flight

  #pragma unroll
  for (int L = 0; L < 3; ++L) {
    const bf16_t* hs = (L == 1) ? hB : hA;   // compile-time under unroll
    bf16_t*       hd = (L == 0) ? hB : hA;
    const bf16_t* Wl   = Wt + L * 65536 + wave * 16384;
    const float*  bias = (L == 0) ? g2b : (L == 1) ? g3b : g4b;

    f32x4 acc[4][4];           // [nt][mt]
    #pragma unroll
    for (int nt = 0; nt < 4; ++nt)
      #pragma unroll
      for (int mt = 0; mt < 4; ++mt)
        #pragma unroll
        for (int e = 0; e < 4; ++e) acc[nt][mt][e] = 0.f;

    #pragma unroll
    for (int ks = 0; ks < 8; ++ks) {
      bf16x8 wf[4], hf[4];
      #pragma unroll
      for (int nt = 0; nt < 4; ++nt)
        wf[nt] = (ks == 0) ? wf0[nt]
                 : *(const bf16x8*)&Wl[((nt * 8 + ks) * 64 + lane) * 8];
      #pragma unroll
      for (int mt = 0; mt < 4; ++mt)
        hf[mt] = *(const bf16x8*)&hs[((mt * 8 + ks) * 64 + lane) * 8];
      __builtin_amdgcn_s_setprio(1);
      #pragma unroll
      for (int nt = 0; nt < 4; ++nt)
        #pragma unroll
        for (int mt = 0; mt < 4; ++mt)
          acc[nt][mt] = __builtin_amdgcn_mfma_f32_16x16x32_bf16(
              wf[nt], hf[mt], acc[nt][mt], 0, 0, 0);
      __builtin_amdgcn_s_setprio(0);
    }
    // NO barrier here: reads were from hs, writes go to hd (disjoint).

    if (L < 2) {
      // D value (nt,mt,e): n = wave*64+nt*16+q*4+e (next layer's k),
      // m = mt*16+r.  Fragment-linear write into hd.
      #pragma unroll
      for (int nt = 0; nt < 4; ++nt) {
        int k0  = wave * 64 + nt * 16 + q * 4;
        float4 bv = *(const float4*)&bias[k0];
        int ks_ = k0 >> 5, rem = k0 & 31;
        int qp  = rem >> 3, e0 = rem & 7;     // e0 in {0,4}
        #pragma unroll
        for (int mt = 0; mt < 4; ++mt) {
          bf16x4 v;
          v[0] = (bf16_t)fmaxf(acc[nt][mt][0] + bv.x, 0.f);
          v[1] = (bf16_t)fmaxf(acc[nt][mt][1] + bv.y, 0.f);
          v[2] = (bf16_t)fmaxf(acc[nt][mt][2] + bv.z, 0.f);
          v[3] = (bf16_t)fmaxf(acc[nt][mt][3] + bv.w, 0.f);
          int off = ((mt * 8 + ks_) * 64 + qp * 16 + r) * 8 + e0;
          *(bf16x4*)&hd[off] = v;
        }
      }
      // next layer's ks0 W loads issue here and stay in flight across the
      // soft barrier (no vmcnt drain).
      if (L == 0) PREFETCH_WF0(1)
      else        PREFETCH_WF0(2)
      SOFTBAR();               // hd visible before next layer reads it
    } else {
      // last layer: bias+relu fp32, sum over the 64 m-rows (mt in-register,
      // then the 16 r-lanes), plain float4 partial store (no atomics).
      #pragma unroll
      for (int nt = 0; nt < 4; ++nt) {
        int k0 = wave * 64 + nt * 16 + q * 4;
        float4 bv = *(const float4*)&bias[k0];
        float p0 = 0.f, p1 = 0.f, p2 = 0.f, p3 = 0.f;
        #pragma unroll
        for (int mt = 0; mt < 4; ++mt) {
          p0 += fmaxf(acc[nt][mt][0] + bv.x, 0.f);
          p1 += fmaxf(acc[nt][mt][1] + bv.y, 0.f);
          p2 += fmaxf(acc[nt][mt][2] + bv.z, 0.f);
          p3 += fmaxf(acc[nt][mt][3] + bv.w, 0.f);
        }
        #pragma unroll
        for (int d = 1; d < 16; d <<= 1) {
          p0 += __shfl_xor(p0, d, 64);
          p1 += __shfl_xor(p1, d, 64);
          p2 += __shfl_xor(p2, d, 64);
          p3 += __shfl_xor(p3, d, 64);
        }
        if (r == 0) {
          float4 pv = make_float4(p0, p1, p2, p3);
          *(float4*)&part[(size_t)bx * 256 + k0] = pv;
        }
      }
    }
  }
#undef PREFETCH_WF0
}

// ---------------- partial reduce + f-MLP + log_softmax (tiny, fp32) --------
// 4-way accumulator splits break the 256-deep serial FMA dependency chains.
__global__ __launch_bounds__(256) void rn_f_kernel(
    const float* __restrict__ part,
    const float* __restrict__ f1w, const float* __restrict__ f1b,
    const float* __restrict__ f2w, const float* __restrict__ f2b,
    const float* __restrict__ f3w, const float* __restrict__ f3b,
    float* __restrict__ out)
{
  __shared__ float xs[256], t1[256], t2[256], lg[28], lse[1];
  int b = blockIdx.x, tid = threadIdx.x;
  // reduce the 64 per-i partials of batch b (coalesced 1 KB/wave per iter)
  {
    float s0 = 0.f, s1 = 0.f, s2 = 0.f, s3 = 0.f;
    const float* pb = part + (size_t)b * 64 * 256;
    #pragma unroll 4
    for (int i = 0; i < 64; i += 4) {
      s0 += pb[(i + 0) * 256 + tid];
      s1 += pb[(i + 1) * 256 + tid];
      s2 += pb[(i + 2) * 256 + tid];
      s3 += pb[(i + 3) * 256 + tid];
    }
    xs[tid] = (s0 + s1) + (s2 + s3);
  }
  __syncthreads();
  {
    float a0 = 0.f, a1 = 0.f, a2 = 0.f, a3 = 0.f;
    for (int k = 0; k < 256; k += 4) {
      a0 += xs[k + 0] * f1w[(k + 0) * 256 + tid];
      a1 += xs[k + 1] * f1w[(k + 1) * 256 + tid];
      a2 += xs[k + 2] * f1w[(k + 2) * 256 + tid];
      a3 += xs[k + 3] * f1w[(k + 3) * 256 + tid];
    }
    t1[tid] = fmaxf(f1b[tid] + (a0 + a1) + (a2 + a3), 0.f);
  }
  __syncthreads();
  {
    float a0 = 0.f, a1 = 0.f, a2 = 0.f, a3 = 0.f;
    for (int k = 0; k < 256; k += 4) {
      a0 += t1[k + 0] * f2w[(k + 0) * 256 + tid];
      a1 += t1[k + 1] * f2w[(k + 1) * 256 + tid];
      a2 += t1[k + 2] * f2w[(k + 2) * 256 + tid];
      a3 += t1[k + 3] * f2w[(k + 3) * 256 + tid];
    }
    t2[tid] = fmaxf(f2b[tid] + (a0 + a1) + (a2 + a3), 0.f);
  }
  __syncthreads();
  if (tid < 28) {
    float a0 = 0.f, a1 = 0.f, a2 = 0.f, a3 = 0.f;
    for (int k = 0; k < 256; k += 4) {
      a0 += t2[k + 0] * f3w[(k + 0) * 28 + tid];
      a1 += t2[k + 1] * f3w[(k + 1) * 28 + tid];
      a2 += t2[k + 2] * f3w[(k + 2) * 28 + tid];
      a3 += t2[k + 3] * f3w[(k + 3) * 28 + tid];
    }
    lg[tid] = f3b[tid] + (a0 + a1) + (a2 + a3);
  }
  __syncthreads();
  if (tid == 0) {
    float m = lg[0];
    for (int j = 1; j < 28; ++j) m = fmaxf(m, lg[j]);
    float se = 0.f;
    for (int j = 0; j < 28; ++j) se += expf(lg[j] - m);
    lse[0] = m + logf(se);
  }
  __syncthreads();
  if (tid < 28) out[b * 28 + tid] = lg[tid] - lse[0];
}

// ---------------------------------------------------------------------------
extern "C" void kernel_launch(void* const* d_in, const int* in_sizes, int n_in,
                              void* d_out, int out_size, void* d_ws, size_t ws_size,
                              hipStream_t stream) {
  (void)in_sizes; (void)n_in; (void)out_size; (void)ws_size;
  const float* x   = (const float*)d_in[0];
  const float* qst = (const float*)d_in[1];
  const float* g1w = (const float*)d_in[2];
  const float* g1b = (const float*)d_in[3];
  const float* g2w = (const float*)d_in[4];
  const float* g2b = (const float*)d_in[5];
  const float* g3w = (const float*)d_in[6];
  const float* g3b = (const float*)d_in[7];
  const float* g4w = (const float*)d_in[8];
  const float* g4b = (const float*)d_in[9];
  const float* f1w = (const float*)d_in[10];
  const float* f1b = (const float*)d_in[11];
  const float* f2w = (const float*)d_in[12];
  const float* f2b = (const float*)d_in[13];
  const float* f3w = (const float*)d_in[14];
  const float* f3b = (const float*)d_in[15];
  float* out = (float*)d_out;

  float*  Ap   = (float*)d_ws;
  float*  C    = Ap + 4096 * 256;
  bf16_t* Wt   = (bf16_t*)(C + 4096 * 256);
  float*  part = (float*)((char*)Wt + 3 * 65536 * sizeof(bf16_t));

  rn_prep_kernel<<<256 + 48, 256, 0, stream>>>(
      x, qst, g1w, g1b, g2w, g3w, g4w, Ap, C, Wt);
  rn_main_kernel<<<4096, 256, 0, stream>>>(Ap, C, Wt, g2b, g3b, g4b, part);
  rn_f_kernel<<<64, 256, 0, stream>>>(part, f1w, f1b, f2w, f2b, f3w, f3b, out);
}

// Round 18
// 220.426 us; speedup vs baseline: 1.1148x; 1.0012x over previous
//
#include <hip/hip_runtime.h>

typedef __bf16 bf16_t;
typedef __bf16 bf16x8 __attribute__((ext_vector_type(8)));
typedef __bf16 bf16x4 __attribute__((ext_vector_type(4)));
typedef float  f32x4  __attribute__((ext_vector_type(4)));

// ---------------------------------------------------------------------------
// Workspace layout (floats unless noted):
//   Ap : [64][16384] f32  xf@W1[0:26] in h-FRAGMENT-LINEAR order:
//        slot ((jt*8+it)*64 + q*16 + r)*8 + e = A[b][jt*16+r][it*32+q*8+e]
//   C  : [4096][256] f32  (xf @ W1[26:52] + qst @ W1[52:180] + b1)
//   Wt : 3 x [256][256] bf16 in MFMA A-fragment layout:
//        [mat][tile16(no>>4)][ks(k>>5)][lane(q*16+r)][e]
//   part : [2048][256] f32  per-block partial pair-sums (i-pair summed)
//
// h in LDS: B-fragment-linear  h[chunk = mt*8+ks][lane = q*16+r][e]
//   <-> h[m = mt*16+r][k = ks*32+q*8+e]  -> all LDS ops lane-contiguous,
//   zero bank conflicts by construction.
//
// Round 18 = r17 (220.7us total / 121.8 main, verified) + build/L2 overlap:
// each block processes TWO i-values sequentially.  During L2(i0) -- which
// only READS hA -- build(i1) writes the free hB in the SAME barrier
// interval (disjoint LDS sets -> race-free).  Hides one build per 2 i's
// under L2's MFMAs, halves block ramps, and both reduces accumulate in
// registers -> one partial store per block (part + f-reduce halve).
// No register pinning (r13 lesson): A re-read from L2 (16 KB, trivial).
//
// Phase/race audit (SB = soft barrier; all block-uniform):
//   build(i0)->hA                                |SB|
//   L0(i0): rd hA, wr hB, prefetch W1            |SB|
//   L1(i0): rd hB, wr hA, prefetch W2            |SB|
//   L2(i0): rd hA  +  build(i1)->hB, prefetch W0 |SB|   <- merged phase
//   L0(i1): rd hB, wr hA, prefetch W1            |SB|
//   L1(i1): rd hA, wr hB, prefetch W2            |SB|
//   L2(i1): rd hB -> store pr
// Every read-set/write-set pair between consecutive SBs is disjoint.
// ---------------------------------------------------------------------------

// ---------------- prep: Ap, C, weight fragment-relayout ---------------------
__global__ __launch_bounds__(256) void rn_prep_kernel(
    const float* __restrict__ x, const float* __restrict__ qst,
    const float* __restrict__ g1w, const float* __restrict__ g1b,
    const float* __restrict__ g2w, const float* __restrict__ g3w,
    const float* __restrict__ g4w,
    float* __restrict__ Ap, float* __restrict__ C,
    bf16_t* __restrict__ Wt)
{
  __shared__ float T[64][65];   // transpose tile (only used by that branch)
  int blk = blockIdx.x;
  int n   = threadIdx.x;  // 0..255
  if (blk < 256) {
    // block = (b, jg): rows jg*16 .. jg*16+15 of batch b; thread = output col n
    int b  = blk >> 2;
    int jg = (blk & 3) * 16;
    // 4-way split of the 128-deep qst dot-product chain (r17: verified)
    float q0 = 0.f, q1 = 0.f, q2 = 0.f, q3 = 0.f;
    const float* qb = qst + b * 128;
    #pragma unroll 4
    for (int qi = 0; qi < 128; qi += 4) {
      q0 += qb[qi + 0] * g1w[(52 + qi + 0) * 256 + n];
      q1 += qb[qi + 1] * g1w[(52 + qi + 1) * 256 + n];
      q2 += qb[qi + 2] * g1w[(52 + qi + 2) * 256 + n];
      q3 += qb[qi + 3] * g1w[(52 + qi + 3) * 256 + n];
    }
    float accQ = g1b[n] + (q0 + q1) + (q2 + q3);

    float w24 = g1w[24 * 256 + n], w25 = g1w[25 * 256 + n];
    float w50 = g1w[50 * 256 + n], w51 = g1w[51 * 256 + n];
    float accA[16], accC[16];
    #pragma unroll
    for (int t = 0; t < 16; ++t) {
      int j = jg + t;
      // faithful to (a/d - d/2)/(d/2.0) float arithmetic, d=8 (exact pow2 ops)
      float cx = ((float)j * 0.125f - 4.0f) * 0.25f;
      float cy = ((float)(j & 7) - 4.0f) * 0.25f;
      accA[t] = cx * w24 + cy * w25;
      accC[t] = accQ + cx * w50 + cy * w51;
    }
    for (int c = 0; c < 24; ++c) {
      float wa = g1w[c * 256 + n];
      float wc = g1w[(26 + c) * 256 + n];
      const float* xc = x + (b * 24 + c) * 64 + jg;
      #pragma unroll
      for (int t = 0; t < 16; ++t) {
        float xv = xc[t];   // uniform per thread -> scalar load
        accA[t] += xv * wa;
        accC[t] += xv * wc;
      }
    }
    // A in fragment-linear order: j = jt*16 + t (jt = blk&3, r = t), k = n.
    int jt = blk & 3;
    int itA = n >> 5, qA = (n >> 3) & 3, eA = n & 7;
    int baseA = b * 16384 + (jt * 8 + itA) * 512 + qA * 128 + eA;
    #pragma unroll
    for (int t = 0; t < 16; ++t) {
      Ap[baseA + t * 8] = accA[t];
      C[(b * 64 + jg + t) * 256 + n] = accC[t];
    }
  } else {
    // LDS-tiled transpose: g2/g3/g4 [in(k)][out(no)] f32 -> bf16 fragment
    // layout: element (no,k) -> [(no>>4)*8 + (k>>5)][((k>>3)&3)*16 + (no&15)][k&7]
    int t   = blk - 256;
    int mat = t >> 4;                 // 0..2
    int tl  = t & 15;                 // 4x4 tiles of 64x64
    int kt  = (tl & 3) * 64;
    int nt_ = (tl >> 2) * 64;
    const float* W = (mat == 0) ? g2w : (mat == 1 ? g3w : g4w);
    int lane = n & 63, w = n >> 6;
    #pragma unroll
    for (int it = 0; it < 16; ++it) {
      int kl = w * 16 + it;
      T[kl][lane] = W[(kt + kl) * 256 + nt_ + lane];   // coalesced 256B/wave
    }
    __syncthreads();
    #pragma unroll
    for (int it = 0; it < 16; ++it) {
      int nl  = w * 16 + it;
      int no  = nt_ + nl;     // output-neuron index
      int k   = kt + lane;    // input index
      int tile = no >> 4, rr = no & 15;
      int ksI  = k >> 5,  qI = (k >> 3) & 3, e = k & 7;
      int idx  = ((tile * 8 + ksI) * 64 + qI * 16 + rr) * 8 + e;
      Wt[mat * 65536 + idx] = (bf16_t)T[lane][nl];
    }
  }
}

// soft barrier: LDS visibility only; global loads stay in flight across it.
#define SOFTBAR()                                            \
  do {                                                       \
    asm volatile("s_waitcnt lgkmcnt(0)" ::: "memory");       \
    __builtin_amdgcn_s_barrier();                            \
    __builtin_amdgcn_sched_barrier(0);                       \
  } while (0)

// ---------------- main fused g-MLP (layers 2..4) + pair partial-sum --------
// one block per (b, i-pair), TWO sequential i-passes: M = 64 rows each,
// N = K = 256, 4 waves.  Wave w owns n-rows [w*64, w*64+64) and all 64
// m-rows.  Per ks: 4 wf global (1 KB coalesced) + 4 hf LDS -> 16 MFMA.
// build(i1) overlaps L2(i0) in one barrier interval (disjoint buffers).
__global__ __launch_bounds__(256, 2) void rn_main_kernel(
    const float* __restrict__ Ap, const float* __restrict__ C,
    const bf16_t* __restrict__ Wt,
    const float* __restrict__ g2b, const float* __restrict__ g3b,
    const float* __restrict__ g4b,
    float* __restrict__ part)
{
  __shared__ bf16_t hA[16384];   // 32 KB: [chunk=mt*8+ks][lane][8]
  __shared__ bf16_t hB[16384];   // 32 KB

  int tid  = threadIdx.x;
  int bx0  = blockIdx.x;
  // bijective XCD swizzle (2048 % 8 == 0): 256 consecutive work-units per
  // XCD -> the 32 blocks sharing a batch b stay on one XCD's L2
  int bx   = (bx0 & 7) * 256 + (bx0 >> 3);
  int b    = bx >> 5;          // batch
  int ip   = bx & 31;          // i-pair: i = 2*ip, 2*ip+1
  int lane = tid & 63;
  int wave = tid >> 6;
  int r    = lane & 15;        // 16-dim index within MFMA tile
  int q    = lane >> 4;        // quad: k-run selector / D-row group

  bf16x8 wf0[4];               // next phase's ks=0 W fragments (in flight
                               // across the soft barrier)

#define PREFETCH_WF0(LL)                                                    \
  {                                                                         \
    const bf16_t* Wn = Wt + (LL) * 65536 + wave * 16384;                    \
    _Pragma("unroll")                                                       \
    for (int nt = 0; nt < 4; ++nt)                                          \
      wf0[nt] = *(const bf16x8*)&Wn[(nt * 8 * 64 + lane) * 8];              \
  }

// build h rows of i-value (ip*2 + IOFF) into DST (fragment-linear).
// Ap is pre-arranged so the A read is lane-contiguous; C row is broadcast.
#define BUILD(DST, IOFF)                                                    \
  {                                                                         \
    const float* Apb = Ap + (size_t)b * 16384 + wave * 4096;                \
    const float* Cr  = C + ((size_t)b * 64 + ip * 2 + (IOFF)) * 256;        \
    _Pragma("unroll")                                                       \
    for (int it = 0; it < 8; ++it) {                                        \
      int k0 = it * 32 + q * 8;                                             \
      const float4 a0 = *(const float4*)(Apb + it * 512 + lane * 8);        \
      const float4 a1 = *(const float4*)(Apb + it * 512 + lane * 8 + 4);    \
      const float4 c0 = *(const float4*)(Cr + k0);                          \
      const float4 c1 = *(const float4*)(Cr + k0 + 4);                      \
      bf16x8 v;                                                             \
      v[0] = (bf16_t)fmaxf(a0.x + c0.x, 0.f);                               \
      v[1] = (bf16_t)fmaxf(a0.y + c0.y, 0.f);                               \
      v[2] = (bf16_t)fmaxf(a0.z + c0.z, 0.f);                               \
      v[3] = (bf16_t)fmaxf(a0.w + c0.w, 0.f);                               \
      v[4] = (bf16_t)fmaxf(a1.x + c1.x, 0.f);                               \
      v[5] = (bf16_t)fmaxf(a1.y + c1.y, 0.f);                               \
      v[6] = (bf16_t)fmaxf(a1.z + c1.z, 0.f);                               \
      v[7] = (bf16_t)fmaxf(a1.w + c1.w, 0.f);                               \
      *(bf16x8*)&(DST)[((wave * 8 + it) * 64 + lane) * 8] = v;              \
    }                                                                       \
  }

  // accumulated i-pair partials (butterfly leaves the sum in all lanes)
  float4 pr[4];
  #pragma unroll
  for (int nt = 0; nt < 4; ++nt) pr[nt] = make_float4(0.f, 0.f, 0.f, 0.f);

  PREFETCH_WF0(0)
  BUILD(hA, 0)
  SOFTBAR();                   // hA visible; wf0 loads still in flight

  #pragma unroll
  for (int ii = 0; ii < 2; ++ii) {
    #pragma unroll
    for (int L = 0; L < 3; ++L) {
      // buffer ping-pong (compile-time under full unroll):
      // ii=0: L0 rd hA wr hB; L1 rd hB wr hA; L2 rd hA (build i1 -> hB)
      // ii=1: L0 rd hB wr hA; L1 rd hA wr hB; L2 rd hB
      const bf16_t* hs;
      bf16_t*       hd;
      if (ii == 0) { hs = (L == 1) ? hB : hA; hd = (L == 0) ? hB : hA; }
      else         { hs = (L == 1) ? hA : hB; hd = (L == 0) ? hA : hB; }
      const bf16_t* Wl   = Wt + L * 65536 + wave * 16384;
      const float*  bias = (L == 0) ? g2b : (L == 1) ? g3b : g4b;

      f32x4 acc[4][4];           // [nt][mt]
      #pragma unroll
      for (int nt = 0; nt < 4; ++nt)
        #pragma unroll
        for (int mt = 0; mt < 4; ++mt)
          #pragma unroll
          for (int e = 0; e < 4; ++e) acc[nt][mt][e] = 0.f;

      #pragma unroll
      for (int ks = 0; ks < 8; ++ks) {
        bf16x8 wf[4], hf[4];
        #pragma unroll
        for (int nt = 0; nt < 4; ++nt)
          wf[nt] = (ks == 0) ? wf0[nt]
                   : *(const bf16x8*)&Wl[((nt * 8 + ks) * 64 + lane) * 8];
        #pragma unroll
        for (int mt = 0; mt < 4; ++mt)
          hf[mt] = *(const bf16x8*)&hs[((mt * 8 + ks) * 64 + lane) * 8];
        __builtin_amdgcn_s_setprio(1);
        #pragma unroll
        for (int nt = 0; nt < 4; ++nt)
          #pragma unroll
          for (int mt = 0; mt < 4; ++mt)
            acc[nt][mt] = __builtin_amdgcn_mfma_f32_16x16x32_bf16(
                wf[nt], hf[mt], acc[nt][mt], 0, 0, 0);
        __builtin_amdgcn_s_setprio(0);
      }
      // NO barrier here: reads were from hs, writes go to hd (disjoint).

      if (L < 2) {
        // D value (nt,mt,e): n = wave*64+nt*16+q*4+e (next layer's k),
        // m = mt*16+r.  Fragment-linear write into hd.
        #pragma unroll
        for (int nt = 0; nt < 4; ++nt) {
          int k0  = wave * 64 + nt * 16 + q * 4;
          float4 bv = *(const float4*)&bias[k0];
          int ks_ = k0 >> 5, rem = k0 & 31;
          int qp  = rem >> 3, e0 = rem & 7;     // e0 in {0,4}
          #pragma unroll
          for (int mt = 0; mt < 4; ++mt) {
            bf16x4 v;
            v[0] = (bf16_t)fmaxf(acc[nt][mt][0] + bv.x, 0.f);
            v[1] = (bf16_t)fmaxf(acc[nt][mt][1] + bv.y, 0.f);
            v[2] = (bf16_t)fmaxf(acc[nt][mt][2] + bv.z, 0.f);
            v[3] = (bf16_t)fmaxf(acc[nt][mt][3] + bv.w, 0.f);
            int off = ((mt * 8 + ks_) * 64 + qp * 16 + r) * 8 + e0;
            *(bf16x4*)&hd[off] = v;
          }
        }
        // next layer's ks0 W loads stay in flight across the soft barrier.
        PREFETCH_WF0(L + 1)
        SOFTBAR();             // hd complete before next layer reads it
      } else {
        // last layer: overlap build(i1) with the reduce (ii=0 only) --
        // build writes the free buffer, L2 only read hs: disjoint.
        if (ii == 0) BUILD(hB, 1)
        // bias+relu fp32, sum over the 64 m-rows (mt in-register, then the
        // 16 r-lanes), accumulate into pr (stored once after both i's).
        #pragma unroll
        for (int nt = 0; nt < 4; ++nt) {
          int k0 = wave * 64 + nt * 16 + q * 4;
          float4 bv = *(const float4*)&bias[k0];
          float p0 = 0.f, p1 = 0.f, p2 = 0.f, p3 = 0.f;
          #pragma unroll
          for (int mt = 0; mt < 4; ++mt) {
            p0 += fmaxf(acc[nt][mt][0] + bv.x, 0.f);
            p1 += fmaxf(acc[nt][mt][1] + bv.y, 0.f);
            p2 += fmaxf(acc[nt][mt][2] + bv.z, 0.f);
            p3 += fmaxf(acc[nt][mt][3] + bv.w, 0.f);
          }
          #pragma unroll
          for (int d = 1; d < 16; d <<= 1) {
            p0 += __shfl_xor(p0, d, 64);
            p1 += __shfl_xor(p1, d, 64);
            p2 += __shfl_xor(p2, d, 64);
            p3 += __shfl_xor(p3, d, 64);
          }
          pr[nt].x += p0; pr[nt].y += p1; pr[nt].z += p2; pr[nt].w += p3;
        }
        if (ii == 0) {
          PREFETCH_WF0(0)      // i1's L0 weights
          SOFTBAR();           // hB (build i1) visible before L0(i1) reads
        }
      }
    }
  }

  // one partial store per block (i-pair summed)
  if (r == 0) {
    #pragma unroll
    for (int nt = 0; nt < 4; ++nt) {
      int k0 = wave * 64 + nt * 16 + q * 4;
      *(float4*)&part[(size_t)bx * 256 + k0] = pr[nt];
    }
  }
#undef PREFETCH_WF0
#undef BUILD
}

// ---------------- partial reduce + f-MLP + log_softmax (tiny, fp32) --------
// 4-way accumulator splits break the serial FMA dependency chains.
__global__ __launch_bounds__(256) void rn_f_kernel(
    const float* __restrict__ part,
    const float* __restrict__ f1w, const float* __restrict__ f1b,
    const float* __restrict__ f2w, const float* __restrict__ f2b,
    const float* __restrict__ f3w, const float* __restrict__ f3b,
    float* __restrict__ out)
{
  __shared__ float xs[256], t1[256], t2[256], lg[28], lse[1];
  int b = blockIdx.x, tid = threadIdx.x;
  // reduce the 32 per-ip partials of batch b (coalesced 1 KB/wave per iter)
  {
    float s0 = 0.f, s1 = 0.f, s2 = 0.f, s3 = 0.f;
    const float* pb = part + (size_t)b * 32 * 256;
    #pragma unroll 4
    for (int i = 0; i < 32; i += 4) {
      s0 += pb[(i + 0) * 256 + tid];
      s1 += pb[(i + 1) * 256 + tid];
      s2 += pb[(i + 2) * 256 + tid];
      s3 += pb[(i + 3) * 256 + tid];
    }
    xs[tid] = (s0 + s1) + (s2 + s3);
  }
  __syncthreads();
  {
    float a0 = 0.f, a1 = 0.f, a2 = 0.f, a3 = 0.f;
    for (int k = 0; k < 256; k += 4) {
      a0 += xs[k + 0] * f1w[(k + 0) * 256 + tid];
      a1 += xs[k + 1] * f1w[(k + 1) * 256 + tid];
      a2 += xs[k + 2] * f1w[(k + 2) * 256 + tid];
      a3 += xs[k + 3] * f1w[(k + 3) * 256 + tid];
    }
    t1[tid] = fmaxf(f1b[tid] + (a0 + a1) + (a2 + a3), 0.f);
  }
  __syncthreads();
  {
    float a0 = 0.f, a1 = 0.f, a2 = 0.f, a3 = 0.f;
    for (int k = 0; k < 256; k += 4) {
      a0 += t1[k + 0] * f2w[(k + 0) * 256 + tid];
      a1 += t1[k + 1] * f2w[(k + 1) * 256 + tid];
      a2 += t1[k + 2] * f2w[(k + 2) * 256 + tid];
      a3 += t1[k + 3] * f2w[(k + 3) * 256 + tid];
    }
    t2[tid] = fmaxf(f2b[tid] + (a0 + a1) + (a2 + a3), 0.f);
  }
  __syncthreads();
  if (tid < 28) {
    float a0 = 0.f, a1 = 0.f, a2 = 0.f, a3 = 0.f;
    for (int k = 0; k < 256; k += 4) {
      a0 += t2[k + 0] * f3w[(k + 0) * 28 + tid];
      a1 += t2[k + 1] * f3w[(k + 1) * 28 + tid];
      a2 += t2[k + 2] * f3w[(k + 2) * 28 + tid];
      a3 += t2[k + 3] * f3w[(k + 3) * 28 + tid];
    }
    lg[tid] = f3b[tid] + (a0 + a1) + (a2 + a3);
  }
  __syncthreads();
  if (tid == 0) {
    float m = lg[0];
    for (int j = 1; j < 28; ++j) m = fmaxf(m, lg[j]);
    float se = 0.f;
    for (int j = 0; j < 28; ++j) se += expf(lg[j] - m);
    lse[0] = m + logf(se);
  }
  __syncthreads();
  if (tid < 28) out[b * 28 + tid] = lg[tid] - lse[0];
}

// ---------------------------------------------------------------------------
extern "C" void kernel_launch(void* const* d_in, const int* in_sizes, int n_in,
                              void* d_out, int out_size, void* d_ws, size_t ws_size,
                              hipStream_t stream) {
  (void)in_sizes; (void)n_in; (void)out_size; (void)ws_size;
  const float* x   = (const float*)d_in[0];
  const float* qst = (const float*)d_in[1];
  const float* g1w = (const float*)d_in[2];
  const float* g1b = (const float*)d_in[3];
  const float* g2w = (const float*)d_in[4];
  const float* g2b = (const float*)d_in[5];
  const float* g3w = (const float*)d_in[6];
  const float* g3b = (const float*)d_in[7];
  const float* g4w = (const float*)d_in[8];
  const float* g4b = (const float*)d_in[9];
  const float* f1w = (const float*)d_in[10];
  const float* f1b = (const float*)d_in[11];
  const float* f2w = (const float*)d_in[12];
  const float* f2b = (const float*)d_in[13];
  const float* f3w = (const float*)d_in[14];
  const float* f3b = (const float*)d_in[15];
  float* out = (float*)d_out;

  float*  Ap   = (float*)d_ws;
  float*  C    = Ap + 4096 * 256;
  bf16_t* Wt   = (bf16_t*)(C + 4096 * 256);
  float*  part = (float*)((char*)Wt + 3 * 65536 * sizeof(bf16_t));

  rn_prep_kernel<<<256 + 48, 256, 0, stream>>>(
      x, qst, g1w, g1b, g2w, g3w, g4w, Ap, C, Wt);
  rn_main_kernel<<<2048, 256, 0, stream>>>(Ap, C, Wt, g2b, g3b, g4b, part);
  rn_f_kernel<<<64, 256, 0, stream>>>(part, f1w, f1b, f2w, f2b, f3w, f3b, out);
}